// Round 1
// baseline (659.623 us; speedup 1.0000x reference)
//
#include <hip/hip_runtime.h>
#include <hip/hip_bf16.h>
#include <math.h>

#define BNROWS (4096*32)   // 131072
#define RB     64          // rows per block = 2 states
#define LN32   3.4657359027997265f

typedef __attribute__((ext_vector_type(8))) short bf16x8;
typedef __attribute__((ext_vector_type(4))) float f32x4;

static __device__ __forceinline__ ushort f2bf(float x) {
    union { __hip_bfloat16 h; ushort u; } cv;
    cv.h = __float2bfloat16(x);
    return cv.u;
}

// ---------------------------------------------------------------------------
// Pack weights into MFMA fragment order (lane-contiguous 16B loads).
// Lane (q,m): element j -> W[k = c*32 + q*8 + j][n = tile*16 + m].
__global__ void prep_pack(const float* __restrict__ w1,
                          const float* __restrict__ w2,
                          ushort* __restrict__ pB1, ushort* __restrict__ pB2,
                          ushort* __restrict__ pB3, ushort* __restrict__ pB4) {
    int g = blockIdx.x * 256 + threadIdx.x;   // 19968 total
    ushort out[8];
    ushort* dst;
    if (g < 3072) {
        int lane = g & 63, gc = g >> 6;
        int t = gc / 3, c = gc % 3;
        int m = lane & 15, q = lane >> 4, n = t * 16 + m;
        #pragma unroll
        for (int j = 0; j < 8; ++j) {
            int k = c * 32 + q * 8 + j;
            out[j] = f2bf((k < 80) ? w1[k * 256 + n] : 0.f);
        }
        dst = &pB1[g * 8];
    } else if (g < 11264) {
        int gg = g - 3072;
        int lane = gg & 63, gc = gg >> 6;
        int t = gc >> 3, c = gc & 7;
        int m = lane & 15, q = lane >> 4, n = t * 16 + m;
        #pragma unroll
        for (int j = 0; j < 8; ++j)
            out[j] = f2bf(w2[(c * 32 + q * 8 + j) * 256 + n]);
        dst = &pB2[gg * 8];
    } else if (g < 19456) {
        int gg = g - 11264;
        int lane = gg & 63, gc = gg >> 6;
        int t = gc >> 3, c = gc & 7;
        int m = lane & 15, q = lane >> 4;
        #pragma unroll
        for (int j = 0; j < 8; ++j)
            out[j] = f2bf(w2[(t * 16 + m) * 256 + c * 32 + q * 8 + j]);
        dst = &pB3[gg * 8];
    } else if (g < 19968) {
        int gg = g - 19456;
        int lane = gg & 63, c = gg >> 6;
        int m = lane & 15, q = lane >> 4;
        #pragma unroll
        for (int j = 0; j < 8; ++j)
            out[j] = f2bf(w1[(64 + m) * 256 + c * 32 + q * 8 + j]);
        dst = &pB4[gg * 8];
    } else return;
    *(uint4*)dst = *(uint4*)out;
}

// ---------------------------------------------------------------------------
// Fully fused 3-step SVGD pipeline. One block = 64 rows = 2 states.
// Per step: MLP fwd+VJP (round-6 MFMA structure, unchanged) -> SVGD tail.
// a (f32 Xs), score (S), logp stay on-chip across steps; obs staged to bf16
// once. SVGD scratch overlays B0 (dead after phase E). LDS total 54528 B
// -> 3 blocks/CU preserved (54528*3 = 163584 <= 163840).
__global__ __launch_bounds__(512) void fused_svgd(
    const float* __restrict__ obs,      // [BN,64] f32
    const float* __restrict__ a_in,     // [BN,16]
    const float* __restrict__ b1,       // [256]
    const float* __restrict__ b2,       // [256]
    const float* __restrict__ w3,       // [256]
    const float* __restrict__ b3,       // [1]
    const ushort* __restrict__ pB1, const ushort* __restrict__ pB2,
    const ushort* __restrict__ pB3, const ushort* __restrict__ pB4,
    float* __restrict__ a_out,          // [BN,16]
    float* __restrict__ logp_out,       // [BN]
    float* __restrict__ qout)           // [BN]
{
    __shared__ __align__(16) ushort B0[RB * 264];   // h1 -> dz2 -> dz1 -> svgd scratch
    __shared__ __align__(16) ushort B1s[RB * 104];  // h0 = [obs | a | 0pad]
    __shared__ __align__(16) float  Xs[RB * 17];    // current a (f32), persistent
    __shared__ float bias1[256], bias2[256], w3s[256];

    // ---- SVGD overlay on B0 (B0 is dead from phase-E barrier to next phase B)
    float*    const Sv     = (float*)B0;            // [64*17]  floats 0..1087
    float*    const KM     = (float*)B0 + 1088;     // [64*40]  1088..3639
    int*      const hist   = (int*)B0 + 3648;       // [2048]   3648..5695 (packed 2x16b)
    int*      const wsum   = (int*)B0 + 5696;       // [2][4]
    int*      const redc   = (int*)B0 + 5704;       // [2][4]
    unsigned* const redm   = (unsigned*)B0 + 5712;  // [2][4]
    int*      const bbin2  = (int*)B0 + 5720;       // [2]
    int*      const bexcl2 = (int*)B0 + 5722;       // [2]
    float*    const gamma2 = (float*)B0 + 5724;     // [2]

    const int tid  = threadIdx.x;
    const int row0 = blockIdx.x * RB;

    // ---- one-time staging: obs f32 -> bf16 into B1s (kills obs_to_bf16 kernel)
    {
        int r = tid >> 3, ch = tid & 7;             // 512 units exactly
        const float* op = &obs[(size_t)(row0 + r) * 64 + ch * 8];
        float4 v0 = *(const float4*)op;
        float4 v1 = *(const float4*)(op + 4);
        ushort o[8];
        o[0] = f2bf(v0.x); o[1] = f2bf(v0.y); o[2] = f2bf(v0.z); o[3] = f2bf(v0.w);
        o[4] = f2bf(v1.x); o[5] = f2bf(v1.y); o[6] = f2bf(v1.z); o[7] = f2bf(v1.w);
        *(uint4*)&B1s[r * 104 + ch * 8] = *(uint4*)o;
    }
    #pragma unroll
    for (int u = 0; u < 2; ++u) {                   // X init (f32 a, exact copy)
        int idx = tid + 512 * u;
        Xs[(idx >> 4) * 17 + (idx & 15)] = a_in[(size_t)row0 * 16 + idx];
    }
    if (tid < 256) {
        int r = tid >> 2, d0 = (tid & 3) * 4;
        ushort4 zv; zv.x = zv.y = zv.z = zv.w = 0;
        *(ushort4*)&B1s[r * 104 + 80 + d0] = zv;    // zero pad cols [80,96)
        bias1[tid] = b1[tid]; bias2[tid] = b2[tid]; w3s[tid] = w3[tid];
    }
    // q init: rows are block-exclusive; waves atomicAdd partials at s==2.
    if (tid < 64) qout[row0 + tid] = b3[0];
    __syncthreads();

    const int lane = tid & 63;
    const int w    = tid >> 6;        // wave 0..7 -> col-tiles {2w, 2w+1}
    const int m    = lane & 15;
    const int q    = lane >> 4;
    const int qk   = q * 8;
    const int st   = tid >> 8;        // state within block (0/1)
    const int t8   = tid & 255;       // thread id within state
    const int wv4  = w & 3;           // wave within state

    float lgp[4] = {0.f, 0.f, 0.f, 0.f};   // logp accumulator (lanes tid&31==0)

    #pragma unroll 1
    for (int s = 0; s < 3; ++s) {
        // ---- Phase A': a (f32 in Xs) -> bf16 into B1s cols [64,80)
        {
            int r = tid >> 3, cp = (tid & 7) * 2;
            ushort2 pv;
            pv.x = f2bf(Xs[r * 17 + cp]);
            pv.y = f2bf(Xs[r * 17 + cp + 1]);
            *(ushort2*)&B1s[r * 104 + 64 + cp] = pv;
        }
        __syncthreads();                                   // (1)

        f32x4 acc[4][2];
        unsigned relumask = 0u;

        // ---- Phase B: z1 = h0 @ w1 (+b1) ; relu -> B0 ; mask -> regs
        #pragma unroll
        for (int tc = 0; tc < 2; ++tc)
            #pragma unroll
            for (int rt = 0; rt < 4; ++rt) acc[rt][tc] = (f32x4){0.f, 0.f, 0.f, 0.f};
        for (int c = 0; c < 3; ++c) {
            bf16x8 af[4];
            #pragma unroll
            for (int rt = 0; rt < 4; ++rt)
                af[rt] = *(const bf16x8*)&B1s[(rt * 16 + m) * 104 + c * 32 + qk];
            #pragma unroll
            for (int tc = 0; tc < 2; ++tc) {
                bf16x8 wfr = *(const bf16x8*)&pB1[(((w * 2 + tc) * 3 + c) * 64 + lane) * 8];
                #pragma unroll
                for (int rt = 0; rt < 4; ++rt)
                    acc[rt][tc] = __builtin_amdgcn_mfma_f32_16x16x32_bf16(wfr, af[rt], acc[rt][tc], 0, 0, 0);
            }
        }
        #pragma unroll
        for (int tc = 0; tc < 2; ++tc) {
            const float4 bv = *(const float4*)&bias1[(w * 2 + tc) * 16 + q * 4];
            const float bva[4] = {bv.x, bv.y, bv.z, bv.w};
            #pragma unroll
            for (int rt = 0; rt < 4; ++rt) {
                ushort4 pk;
                float z0 = acc[rt][tc][0] + bva[0];
                float z1 = acc[rt][tc][1] + bva[1];
                float z2 = acc[rt][tc][2] + bva[2];
                float z3 = acc[rt][tc][3] + bva[3];
                if (z0 > 0.f) relumask |= 1u << (rt * 8 + tc * 4 + 0);
                if (z1 > 0.f) relumask |= 1u << (rt * 8 + tc * 4 + 1);
                if (z2 > 0.f) relumask |= 1u << (rt * 8 + tc * 4 + 2);
                if (z3 > 0.f) relumask |= 1u << (rt * 8 + tc * 4 + 3);
                pk.x = f2bf(fmaxf(z0, 0.f)); pk.y = f2bf(fmaxf(z1, 0.f));
                pk.z = f2bf(fmaxf(z2, 0.f)); pk.w = f2bf(fmaxf(z3, 0.f));
                *(ushort4*)&B0[(rt * 16 + m) * 264 + (w * 2 + tc) * 16 + q * 4] = pk;
            }
        }
        __syncthreads();                                   // (2)

        // ---- Phase C: z2 = h1 @ w2 (+b2) ; q partials (s==2) ; dz2 -> B0
        #pragma unroll
        for (int tc = 0; tc < 2; ++tc)
            #pragma unroll
            for (int rt = 0; rt < 4; ++rt) acc[rt][tc] = (f32x4){0.f, 0.f, 0.f, 0.f};
        for (int c = 0; c < 8; ++c) {
            bf16x8 af[4];
            #pragma unroll
            for (int rt = 0; rt < 4; ++rt)
                af[rt] = *(const bf16x8*)&B0[(rt * 16 + m) * 264 + c * 32 + qk];
            #pragma unroll
            for (int tc = 0; tc < 2; ++tc) {
                bf16x8 wfr = *(const bf16x8*)&pB2[(((w * 2 + tc) * 8 + c) * 64 + lane) * 8];
                #pragma unroll
                for (int rt = 0; rt < 4; ++rt)
                    acc[rt][tc] = __builtin_amdgcn_mfma_f32_16x16x32_bf16(wfr, af[rt], acc[rt][tc], 0, 0, 0);
            }
        }
        __syncthreads();                                   // (3)
        {
            float qp[4] = {0.f, 0.f, 0.f, 0.f};
            #pragma unroll
            for (int tc = 0; tc < 2; ++tc) {
                const float4 bv = *(const float4*)&bias2[(w * 2 + tc) * 16 + q * 4];
                const float4 wv = *(const float4*)&w3s[(w * 2 + tc) * 16 + q * 4];
                const float bva[4] = {bv.x, bv.y, bv.z, bv.w};
                const float wva[4] = {wv.x, wv.y, wv.z, wv.w};
                #pragma unroll
                for (int rt = 0; rt < 4; ++rt) {
                    ushort4 pk; float dz[4];
                    #pragma unroll
                    for (int i = 0; i < 4; ++i) {
                        float z = acc[rt][tc][i] + bva[i];
                        if (z > 0.f) { qp[rt] += z * wva[i]; dz[i] = wva[i]; }
                        else         { dz[i] = 0.f; }
                    }
                    pk.x = f2bf(dz[0]); pk.y = f2bf(dz[1]);
                    pk.z = f2bf(dz[2]); pk.w = f2bf(dz[3]);
                    *(ushort4*)&B0[(rt * 16 + m) * 264 + (w * 2 + tc) * 16 + q * 4] = pk;
                }
            }
            if (s == 2) {
                #pragma unroll
                for (int rt = 0; rt < 4; ++rt) {
                    float v = qp[rt];
                    v += __shfl_xor(v, 16); v += __shfl_xor(v, 32);
                    if (q == 0) atomicAdd(&qout[row0 + rt * 16 + m], v);
                }
            }
        }
        __syncthreads();                                   // (4)

        // ---- Phase D: dh1 = dz2 @ w2^T ; dz1 = dh1 * mask -> B0
        #pragma unroll
        for (int tc = 0; tc < 2; ++tc)
            #pragma unroll
            for (int rt = 0; rt < 4; ++rt) acc[rt][tc] = (f32x4){0.f, 0.f, 0.f, 0.f};
        for (int c = 0; c < 8; ++c) {
            bf16x8 af[4];
            #pragma unroll
            for (int rt = 0; rt < 4; ++rt)
                af[rt] = *(const bf16x8*)&B0[(rt * 16 + m) * 264 + c * 32 + qk];
            #pragma unroll
            for (int tc = 0; tc < 2; ++tc) {
                bf16x8 wfr = *(const bf16x8*)&pB3[(((w * 2 + tc) * 8 + c) * 64 + lane) * 8];
                #pragma unroll
                for (int rt = 0; rt < 4; ++rt)
                    acc[rt][tc] = __builtin_amdgcn_mfma_f32_16x16x32_bf16(wfr, af[rt], acc[rt][tc], 0, 0, 0);
            }
        }
        __syncthreads();                                   // (5)
        #pragma unroll
        for (int rt = 0; rt < 4; ++rt)
            #pragma unroll
            for (int tc = 0; tc < 2; ++tc) {
                ushort4 pk;
                pk.x = f2bf((relumask >> (rt * 8 + tc * 4 + 0)) & 1u ? acc[rt][tc][0] : 0.f);
                pk.y = f2bf((relumask >> (rt * 8 + tc * 4 + 1)) & 1u ? acc[rt][tc][1] : 0.f);
                pk.z = f2bf((relumask >> (rt * 8 + tc * 4 + 2)) & 1u ? acc[rt][tc][2] : 0.f);
                pk.w = f2bf((relumask >> (rt * 8 + tc * 4 + 3)) & 1u ? acc[rt][tc][3] : 0.f);
                *(ushort4*)&B0[(rt * 16 + m) * 264 + (w * 2 + tc) * 16 + q * 4] = pk;
            }
        __syncthreads();                                   // (6)

        // ---- Phase E: score = dz1 @ w1[64:80]^T (waves 0..3, row-tile w)
        f32x4 accE = (f32x4){0.f, 0.f, 0.f, 0.f};
        if (w < 4) {
            for (int c = 0; c < 8; ++c) {
                bf16x8 af = *(const bf16x8*)&B0[(w * 16 + m) * 264 + c * 32 + qk];
                bf16x8 wfr = *(const bf16x8*)&pB4[(c * 64 + lane) * 8];
                accE = __builtin_amdgcn_mfma_f32_16x16x32_bf16(wfr, af, accE, 0, 0, 0);
            }
        }
        __syncthreads();                // (7) all dz1 reads done before overlay write
        if (w < 4) {
            float* Sr = &Sv[(w * 16 + m) * 17 + q * 4];
            Sr[0] = accE[0]; Sr[1] = accE[1]; Sr[2] = accE[2]; Sr[3] = accE[3];
        }
        __syncthreads();                // (8) S visible

        // ================= SVGD tail (2 states, 256 thr each) =================
        // dist^2 bits + P fused; thread owns pairs (i = t8>>5 + 8t, j = t8&31)
        unsigned vb[4]; float pr[4];
        #pragma unroll
        for (int t = 0; t < 4; ++t) {
            int idx = t8 + 256 * t, i = idx >> 5, j = idx & 31;
            int gi = st * 32 + i, gj = st * 32 + j;
            float ss = 0.f, pp = 0.f;
            #pragma unroll
            for (int d = 0; d < 16; ++d) {
                float df = Xs[gi * 17 + d] - Xs[gj * 17 + d];
                ss = fmaf(df, df, ss);
                pp = fmaf(df, Sv[gj * 17 + d], pp);
            }
            vb[t] = __float_as_uint(ss);
            pr[t] = pp;
        }

        // ---- 3-pass radix select: rank-511 value (bit-exact), 2-state packed hist
        unsigned prefix = 0;
        int rank = 511;
        const int addv = 1 << (st * 16);
        #pragma unroll 1
        for (int pass = 0; pass < 3; ++pass) {
            const int sh = (pass == 0) ? 21 : (pass == 1) ? 10 : 0;
            const unsigned dmask = (pass == 2) ? 1023u : 2047u;
            #pragma unroll
            for (int k = 0; k < 4; ++k) hist[tid + 512 * k] = 0;
            __syncthreads();
            #pragma unroll
            for (int t = 0; t < 4; ++t) {
                bool ok = (pass == 0) ||
                          ((vb[t] >> (sh + ((pass == 1) ? 11 : 10))) == prefix);
                if (ok) atomicAdd(&hist[(vb[t] >> sh) & dmask], addv);
            }
            __syncthreads();
            int c[8], ct = 0;
            #pragma unroll
            for (int k = 0; k < 8; ++k) {
                c[k] = (hist[8 * t8 + k] >> (st * 16)) & 0xFFFF;
                ct += c[k];
            }
            int inc = ct;
            #pragma unroll
            for (int off = 1; off < 64; off <<= 1) {
                int tt = __shfl_up(inc, off, 64);
                if (lane >= off) inc += tt;
            }
            if (lane == 63) wsum[st * 4 + wv4] = inc;
            __syncthreads();
            int run = inc - ct;
            for (int ww = 0; ww < wv4; ++ww) run += wsum[st * 4 + ww];
            #pragma unroll
            for (int k = 0; k < 8; ++k) {
                if (c[k] > 0 && rank >= run && rank < run + c[k]) {
                    bbin2[st] = 8 * t8 + k; bexcl2[st] = run;
                }
                run += c[k];
            }
            __syncthreads();
            prefix = (prefix << ((pass == 2) ? 10 : 11)) | (unsigned)bbin2[st];
            rank -= bexcl2[st];
        }
        const float v1 = __uint_as_float(prefix);

        // rank-512 value: v1 again if count(x<=v1)>=513 else min of x>v1
        float med;
        {
            int cle = 0;
            unsigned mgt = 0xFFFFFFFFu;
            #pragma unroll
            for (int t = 0; t < 4; ++t) {
                if (vb[t] <= prefix) cle++;
                else mgt = min(mgt, vb[t]);
            }
            #pragma unroll
            for (int off = 1; off < 64; off <<= 1) {
                cle += __shfl_xor(cle, off);
                mgt = min(mgt, (unsigned)__shfl_xor((int)mgt, off));
            }
            if (lane == 0) { redc[st * 4 + wv4] = cle; redm[st * 4 + wv4] = mgt; }
            __syncthreads();
            int C = redc[st * 4 + 0] + redc[st * 4 + 1] + redc[st * 4 + 2] + redc[st * 4 + 3];
            unsigned M = min(min(redm[st * 4 + 0], redm[st * 4 + 1]),
                             min(redm[st * 4 + 2], redm[st * 4 + 3]));
            float v2 = (C >= 513) ? v1 : __uint_as_float(M);
            med = 0.5f * (v1 + v2);
        }
        const float gamma = 1.0f / (2.0f * (med / LN32 + 1e-8f));
        if (t8 == 0) gamma2[st] = gamma;

        // ---- K: registers + LDS (stride 40: conflict-free writes, bcast reads)
        float kreg[4];
        #pragma unroll
        for (int t = 0; t < 4; ++t) {
            int idx = t8 + 256 * t, i = idx >> 5, j = idx & 31;
            float kk = __expf(-gamma * __uint_as_float(vb[t]));
            kreg[t] = kk;
            KM[(st * 32 + i) * 40 + j] = kk;
        }

        // ---- logp from registers (32-lane butterfly); stays in lgp[] regs
        {
            float a1s[4], a2s[4];
            #pragma unroll
            for (int t = 0; t < 4; ++t) {
                float a1 = kreg[t] * pr[t];
                float a2 = (2.f * gamma * __uint_as_float(vb[t]) - 16.f) * kreg[t];
                #pragma unroll
                for (int off = 1; off < 32; off <<= 1) {
                    a1 += __shfl_xor(a1, off);
                    a2 += __shfl_xor(a2, off);
                }
                a1s[t] = a1; a2s[t] = a2;
            }
            if ((tid & 31) == 0) {
                #pragma unroll
                for (int t = 0; t < 4; ++t) {
                    int i = (t8 >> 5) + 8 * t;
                    float tmp = -2.f * gamma * (a1s[t] + a2s[t]) * (1.f / 32.f);
                    lgp[t] -= 0.1f * tmp;
                    if (s == 2) logp_out[row0 + st * 32 + i] = lgp[t];
                }
            }
        }
        __syncthreads();                // KM + gamma2 visible for phi

        // ---- phi + particle update (512 thr over 1024 (row,d) entries)
        float av[2];
        #pragma unroll
        for (int u = 0; u < 2; ++u) {
            int idx = tid + 512 * u;
            int i = idx >> 4, d = idx & 15;
            int sb = (i >> 5) * 32;
            float g = gamma2[i >> 5];
            float xi = Xs[i * 17 + d];
            float s1 = 0.f, s2 = 0.f;
            #pragma unroll
            for (int j = 0; j < 32; ++j) {
                float kk = KM[i * 40 + j];
                s1 = fmaf(kk, Sv[(sb + j) * 17 + d], s1);
                s2 = fmaf(kk, xi - Xs[(sb + j) * 17 + d], s2);
            }
            float phi = (s1 + 2.f * g * s2) * (1.f / 32.f);
            float t = xi + 0.1f * phi;
            av[u] = fminf(fmaxf(t, -1.f), 1.f);
        }
        __syncthreads();                // all Xs/Sv/KM reads done before X update
        #pragma unroll
        for (int u = 0; u < 2; ++u) {
            int idx = tid + 512 * u;
            Xs[(idx >> 4) * 17 + (idx & 15)] = av[u];
            if (s == 2) a_out[(size_t)row0 * 16 + idx] = av[u];
        }
        __syncthreads();                // Xs visible for next step's Phase A'
    }
}

// ---------------------------------------------------------------------------
extern "C" void kernel_launch(void* const* d_in, const int* in_sizes, int n_in,
                              void* d_out, int out_size, void* d_ws, size_t ws_size,
                              hipStream_t stream) {
    const float* obs = (const float*)d_in[0];
    const float* a0  = (const float*)d_in[1];
    const float* w1  = (const float*)d_in[2];
    const float* b1  = (const float*)d_in[3];
    const float* w2  = (const float*)d_in[4];
    const float* b2  = (const float*)d_in[5];
    const float* w3  = (const float*)d_in[6];
    const float* b3  = (const float*)d_in[7];

    float* out_a    = (float*)d_out;                 // [BN,16]
    float* out_logp = out_a + (size_t)BNROWS * 16;   // [BN]
    float* out_q    = out_logp + BNROWS;             // [BN]

    char* p = (char*)d_ws;
    ushort* pB1 = (ushort*)p; p += 24576 * 2;
    ushort* pB2 = (ushort*)p; p += 65536 * 2;
    ushort* pB3 = (ushort*)p; p += 65536 * 2;
    ushort* pB4 = (ushort*)p;

    prep_pack<<<78, 256, 0, stream>>>(w1, w2, pB1, pB2, pB3, pB4);

    const int MB = BNROWS / RB;   // 2048 blocks, 2 states each
    fused_svgd<<<MB, 512, 0, stream>>>(obs, a0, b1, b2, w3, b3,
                                       pB1, pB2, pB3, pB4,
                                       out_a, out_logp, out_q);
}